// Round 1
// baseline (76077.130 us; speedup 1.0000x reference)
//
#include <hip/hip_runtime.h>
#include <hip/hip_bf16.h>

#define BB 64
#define TT 1000
#define DD 16
#define HH 1024
#define OO 8

// -------- W_h2h transpose: WT[k][j] = W[j][k] (coalesced both sides) --------
__global__ void transpose_w_kernel(const float* __restrict__ W, float* __restrict__ WT) {
    __shared__ float tile[32][33];
    int bx = blockIdx.x, by = blockIdx.y;
    int x = bx * 32 + threadIdx.x;   // k (col of W)
    int y = by * 32 + threadIdx.y;   // j (row of W)
    tile[threadIdx.y][threadIdx.x] = W[y * HH + x];
    __syncthreads();
    int k = bx * 32 + threadIdx.y;
    int j = by * 32 + threadIdx.x;
    WT[k * HH + j] = tile[threadIdx.x][threadIdx.y];
}

// -------- Persistent per-batch RNN kernel: block b owns batch b ------------
// TRANS=true : W arg is W^T [k][j] -> coalesced outer-product loads
// TRANS=false: W arg is W   [j][k] -> per-thread row streaming (fallback)
template <bool TRANS>
__global__ __launch_bounds__(512) void rnn_kernel(
    const float* __restrict__ x,     // [64][1000][16]
    const float* __restrict__ h0,    // [64][1024]
    const float* __restrict__ Wi2h,  // [1024][16]
    const float* __restrict__ W,     // see TRANS
    const float* __restrict__ Wh2o,  // [8][1024]
    float* __restrict__ out_o,       // [64][1000][8]
    float* __restrict__ out_h)       // [64][1000][1024]
{
    const int b  = blockIdx.x;
    const int t0 = threadIdx.x;      // 0..511
    const int j0 = 2 * t0;           // owns units j0, j0+1
    const int wave = t0 >> 6;
    const int lane = t0 & 63;

    __shared__ float th[HH];         // tanh(h) of current step
    __shared__ float xs[DD];         // x[b][t][:]
    __shared__ float ored[8][OO];    // per-wave output partials

    // persistent register caches of the tiny weight slices this thread needs
    float wi[2][DD];
#pragma unroll
    for (int d = 0; d < DD; ++d) {
        wi[0][d] = Wi2h[j0 * DD + d];
        wi[1][d] = Wi2h[(j0 + 1) * DD + d];
    }
    float wo[2][OO];
#pragma unroll
    for (int o = 0; o < OO; ++o) {
        wo[0][o] = Wh2o[o * HH + j0];
        wo[1][o] = Wh2o[o * HH + j0 + 1];
    }

    float h[2] = { h0[b * HH + j0], h0[b * HH + j0 + 1] };
    th[j0]     = tanhf(h[0]);
    th[j0 + 1] = tanhf(h[1]);
    if (t0 < DD) xs[t0] = x[(size_t)(b * TT + 0) * DD + t0];
    __syncthreads();

    for (int t = 0; t < TT; ++t) {
        // ---- z = W_h2h . tanh(h) for this thread's two units ----
        float a0 = 0.f, a1 = 0.f;
        if (TRANS) {
            const float* wptr = W + j0;            // WT[k][j0], stride HH
#pragma unroll 4
            for (int k = 0; k < HH; k += 4) {
                float4 t4 = *(const float4*)&th[k];            // uniform bcast
                float2 w0 = *(const float2*)(wptr + (size_t)(k + 0) * HH);
                float2 w1 = *(const float2*)(wptr + (size_t)(k + 1) * HH);
                float2 w2 = *(const float2*)(wptr + (size_t)(k + 2) * HH);
                float2 w3 = *(const float2*)(wptr + (size_t)(k + 3) * HH);
                a0 += t4.x * w0.x; a1 += t4.x * w0.y;
                a0 += t4.y * w1.x; a1 += t4.y * w1.y;
                a0 += t4.z * w2.x; a1 += t4.z * w2.y;
                a0 += t4.w * w3.x; a1 += t4.w * w3.y;
            }
        } else {
            const float* r0 = W + (size_t)j0 * HH;
            const float* r1 = W + (size_t)(j0 + 1) * HH;
#pragma unroll 4
            for (int k = 0; k < HH; k += 4) {
                float4 t4 = *(const float4*)&th[k];
                float4 wA = *(const float4*)(r0 + k);
                float4 wB = *(const float4*)(r1 + k);
                a0 += t4.x * wA.x + t4.y * wA.y + t4.z * wA.z + t4.w * wA.w;
                a1 += t4.x * wB.x + t4.y * wB.y + t4.z * wB.z + t4.w * wB.w;
            }
        }

        // ---- x projection (D=16, on the fly) ----
        float xp0 = 0.f, xp1 = 0.f;
#pragma unroll
        for (int d = 0; d < DD; ++d) {
            float xv = xs[d];
            xp0 += xv * wi[0][d];
            xp1 += xv * wi[1][d];
        }

        // ---- leaky update ----
        h[0] = 0.9f * h[0] + 0.1f * (a0 + xp0);
        h[1] = 0.9f * h[1] + 0.1f * (a1 + xp1);
        float th0 = tanhf(h[0]);
        float th1 = tanhf(h[1]);

        // ---- store hiddens (coalesced float2) ----
        *(float2*)&out_h[((size_t)b * TT + t) * HH + j0] = make_float2(h[0], h[1]);

        // ---- output partials: out[o] = sum_j th[j]*Wh2o[o][j] ----
        float po[OO];
#pragma unroll
        for (int o = 0; o < OO; ++o) po[o] = th0 * wo[0][o] + th1 * wo[1][o];
#pragma unroll
        for (int s = 32; s > 0; s >>= 1)
#pragma unroll
            for (int o = 0; o < OO; ++o) po[o] += __shfl_down(po[o], s, 64);

        __syncthreads();   // A: all reads of th / xs for step t complete
        if (lane == 0)
#pragma unroll
            for (int o = 0; o < OO; ++o) ored[wave][o] = po[o];
        th[j0]     = th0;
        th[j0 + 1] = th1;
        if (t0 < DD && t + 1 < TT) xs[t0] = x[(size_t)(b * TT + (t + 1)) * DD + t0];
        __syncthreads();   // B: new th/xs/ored published
        if (t0 < OO) {
            float s = 0.f;
#pragma unroll
            for (int w = 0; w < 8; ++w) s += ored[w][t0];
            out_o[((size_t)b * TT + t) * OO + t0] = s;
        }
        // ored is rewritten only after next iteration's sync A -> no race
    }
}

extern "C" void kernel_launch(void* const* d_in, const int* in_sizes, int n_in,
                              void* d_out, int out_size, void* d_ws, size_t ws_size,
                              hipStream_t stream) {
    const float* x    = (const float*)d_in[0];  // [64][1000][16]
    const float* h0   = (const float*)d_in[1];  // [64][1024]
    const float* Wi2h = (const float*)d_in[2];  // [1024][16]
    const float* Wh2h = (const float*)d_in[3];  // [1024][1024]
    const float* Wh2o = (const float*)d_in[4];  // [8][1024]

    float* out_o = (float*)d_out;                       // [64][1000][8]
    float* out_h = out_o + (size_t)BB * TT * OO;        // [64][1000][1024]

    const size_t wt_bytes = (size_t)HH * HH * sizeof(float);
    if (ws_size >= wt_bytes) {
        float* WT = (float*)d_ws;
        transpose_w_kernel<<<dim3(32, 32), dim3(32, 32), 0, stream>>>(Wh2h, WT);
        rnn_kernel<true><<<BB, 512, 0, stream>>>(x, h0, Wi2h, WT, Wh2o, out_o, out_h);
    } else {
        rnn_kernel<false><<<BB, 512, 0, stream>>>(x, h0, Wi2h, Wh2h, Wh2o, out_o, out_h);
    }
}

// Round 2
// 26264.899 us; speedup vs baseline: 2.8965x; 2.8965x over previous
//
#include <hip/hip_runtime.h>
#include <hip/hip_bf16.h>

#define BB 64
#define TT 1000
#define DD 16
#define HH 1024
#define OO 8

#define NGRP 4          // batch groups
#define GB   16         // batches per group
#define SJ   16         // j-units per slice
#define NBLK 256        // NGRP * (HH/SJ)
#define NTH  512

// ---------------------------------------------------------------------------
// Device-scope group barrier: monotonic counter, no reset. Called by tid==0.
// Writers: stores already drained to L2 by __syncthreads (vmcnt(0) before
// s_barrier). __threadfence -> agent fence (buffer_wbl2/inv sc1) pushes them
// past the XCD L2 and invalidates stale lines on the reader side.
// ---------------------------------------------------------------------------
__device__ __forceinline__ void group_barrier(unsigned* c, unsigned target) {
    __threadfence();                                     // release: L2 wb
    atomicAdd(c, 1u);                                    // device scope
    while (__hip_atomic_load(c, __ATOMIC_ACQUIRE, __HIP_MEMORY_SCOPE_AGENT) < target)
        __builtin_amdgcn_s_sleep(2);
    __threadfence();                                     // acquire: L2 inv
}

// ---------------------------------------------------------------------------
// Persistent cooperative RNN kernel.
// Block (bg, js): batches [bg*16, +16), units [js*16, +16).
// W slice resident in LDS. th exchanged via TH[2][NGRP][HH][GB] in d_ws.
// ---------------------------------------------------------------------------
__global__ __launch_bounds__(NTH, 2) void rnn_coop(
    const float* __restrict__ x,     // [64][1000][16]
    const float* __restrict__ h0,    // [64][1024]
    const float* __restrict__ Wi2h,  // [1024][16]
    const float* __restrict__ Wh2h,  // [1024][1024]
    float* __restrict__ out_h,       // [64][1000][1024]
    float* TH,                       // [2][NGRP][HH][GB]
    unsigned* cnt)                   // [NGRP]
{
    __shared__ float Wl [SJ][1028];   // W slice, stride 1028 (16B aligned, 2-way banks)
    __shared__ float THl[GB][1028];   // tanh(h) for the group, [b][k]
    __shared__ float SC [8][GB][17];  // k-split partials [wave][b][j]
    __shared__ float XS [GB][DD];     // x tile for step t

    const int tid = threadIdx.x;
    const int w   = tid >> 6;         // wave 0..7
    const int l   = tid & 63;
    const int bid = blockIdx.x;
    const int bg  = bid & (NGRP - 1);
    const int js  = bid >> 2;         // 0..63

    // ---- stage W slice -> LDS (once) ----
#pragma unroll
    for (int i = 0; i < 8; ++i) {
        int f  = tid + NTH * i;            // float4 index, 4096 total
        int r  = f >> 8;
        int c4 = f & 255;
        float4 v = *(const float4*)&Wh2h[(size_t)(js * SJ + r) * HH + c4 * 4];
        *(float4*)&Wl[r][c4 * 4] = v;
    }

    // ---- finalize-thread state: tid<256 owns (j = tid&15, b = tid>>4) ----
    const int fj = tid & 15, fb = tid >> 4;
    float h = 0.f;
    float wi[DD];
    if (tid < 256) {
        h = h0[(size_t)(bg * GB + fb) * HH + js * SJ + fj];
#pragma unroll
        for (int d = 0; d < DD; ++d) wi[d] = Wi2h[(js * SJ + fj) * DD + d];
        TH[((size_t)(0 * NGRP + bg) * HH + js * SJ + fj) * GB + fb] = tanhf(h);
    }

    __syncthreads();
    if (tid == 0) group_barrier(&cnt[bg], 64u * 1);     // init barrier
    __syncthreads();

    const int jt = l & 15;            // compute role: j within slice
    const int bq = l >> 4;            // compute role: b quad (4 b's)

    for (int t = 0; t < TT; ++t) {
        const int buf = t & 1;
        const float* THr = TH + (size_t)(buf * NGRP + bg) * HH * GB;        // [k][b]
        float*       THw = TH + (size_t)((buf ^ 1) * NGRP + bg) * HH * GB;

        // ---- stage this wave's k-stripe [w*128, +128) of th into LDS ----
        {
            const int kk  = l >> 2;
            const int bq4 = (l & 3) * 4;
#pragma unroll
            for (int i = 0; i < 8; ++i) {
                int k = w * 128 + i * 16 + kk;
                float4 v = *(const float4*)&THr[(size_t)k * GB + bq4];
                THl[bq4 + 0][k] = v.x;
                THl[bq4 + 1][k] = v.y;
                THl[bq4 + 2][k] = v.z;
                THl[bq4 + 3][k] = v.w;
            }
        }
        // ---- stage x tile (wave 0): XS[b][d] = x[bg*16+b][t][d] ----
        if (w == 0) {
            int b = l >> 2, dq = (l & 3) * 4;
            float4 v = *(const float4*)&x[((size_t)(bg * GB + b) * TT + t) * DD + dq];
            *(float4*)&XS[b][dq] = v;
        }
        __builtin_amdgcn_s_waitcnt(0);   // wave-local: stripe writes complete

        // ---- compute: acc[m] = sum_{k in stripe} W[jt][k] * th[bq*4+m][k] ----
        float a0 = 0.f, a1 = 0.f, a2 = 0.f, a3 = 0.f;
        const float* wrow = &Wl[jt][0];
        const float* t0r  = &THl[bq * 4 + 0][0];
        const float* t1r  = &THl[bq * 4 + 1][0];
        const float* t2r  = &THl[bq * 4 + 2][0];
        const float* t3r  = &THl[bq * 4 + 3][0];
#pragma unroll 4
        for (int q = 0; q < 32; ++q) {
            int k = w * 128 + q * 4;
            float4 wv = *(const float4*)&wrow[k];
            float4 v0 = *(const float4*)&t0r[k];
            float4 v1 = *(const float4*)&t1r[k];
            float4 v2 = *(const float4*)&t2r[k];
            float4 v3 = *(const float4*)&t3r[k];
            a0 += wv.x * v0.x; a1 += wv.x * v1.x; a2 += wv.x * v2.x; a3 += wv.x * v3.x;
            a0 += wv.y * v0.y; a1 += wv.y * v1.y; a2 += wv.y * v2.y; a3 += wv.y * v3.y;
            a0 += wv.z * v0.z; a1 += wv.z * v1.z; a2 += wv.z * v2.z; a3 += wv.z * v3.z;
            a0 += wv.w * v0.w; a1 += wv.w * v1.w; a2 += wv.w * v2.w; a3 += wv.w * v3.w;
        }
        SC[w][bq * 4 + 0][jt] = a0;
        SC[w][bq * 4 + 1][jt] = a1;
        SC[w][bq * 4 + 2][jt] = a2;
        SC[w][bq * 4 + 3][jt] = a3;

        __syncthreads();   // all partials + XS visible

        // ---- finalize: tid<256 -> (fj, fb) ----
        if (tid < 256) {
            float z = 0.f;
#pragma unroll
            for (int ww = 0; ww < 8; ++ww) z += SC[ww][fb][fj];
            float xp = 0.f;
#pragma unroll
            for (int d = 0; d < DD; ++d) xp += wi[d] * XS[fb][d];
            h = 0.9f * h + 0.1f * (z + xp);
            float th = tanhf(h);
            out_h[((size_t)(bg * GB + fb) * TT + t) * HH + js * SJ + fj] = h;
            THw[(size_t)(js * SJ + fj) * GB + fb] = th;
        }

        __syncthreads();   // finalize stores drained (vmcnt(0) before barrier)
        if (tid == 0) group_barrier(&cnt[bg], 64u * (t + 2));
        __syncthreads();
    }
}

// ---------------------------------------------------------------------------
// h2o output kernel: out[b][t][o] = sum_j tanh(h[b][t][j]) * Wh2o[o][j]
// ---------------------------------------------------------------------------
__global__ __launch_bounds__(256) void h2o_kernel(
    const float* __restrict__ hs,    // [64][1000][1024]
    const float* __restrict__ Wh2o,  // [8][1024]
    float* __restrict__ out_o)       // [64][1000][8]
{
    __shared__ float Wl[OO * HH];
    for (int i = threadIdx.x; i < OO * HH; i += 256) Wl[i] = Wh2o[i];
    __syncthreads();

    const int w = threadIdx.x >> 6, l = threadIdx.x & 63;
    const size_t nrows = (size_t)BB * TT;
    for (size_t row = (size_t)blockIdx.x * 4 + w; row < nrows; row += (size_t)gridDim.x * 4) {
        const float* hr = hs + row * HH;
        float po[OO] = {0.f};
#pragma unroll
        for (int i = 0; i < 16; ++i) {
            int j = l + 64 * i;
            float th = tanhf(hr[j]);
#pragma unroll
            for (int o = 0; o < OO; ++o) po[o] += th * Wl[o * HH + j];
        }
#pragma unroll
        for (int s = 32; s; s >>= 1)
#pragma unroll
            for (int o = 0; o < OO; ++o) po[o] += __shfl_down(po[o], s, 64);
        if (l == 0) {
#pragma unroll
            for (int o = 0; o < OO; ++o) out_o[row * OO + o] = po[o];
        }
    }
}

// ---------------------------------------------------------------------------
// Fallback (round-1 kernel, W row-major direct) if ws is too small.
// ---------------------------------------------------------------------------
__global__ __launch_bounds__(512) void rnn_fallback(
    const float* __restrict__ x, const float* __restrict__ h0,
    const float* __restrict__ Wi2h, const float* __restrict__ W,
    const float* __restrict__ Wh2o, float* __restrict__ out_o,
    float* __restrict__ out_h)
{
    const int b = blockIdx.x, t0 = threadIdx.x, j0 = 2 * t0;
    const int wave = t0 >> 6, lane = t0 & 63;
    __shared__ float th[HH];
    __shared__ float xs[DD];
    __shared__ float ored[8][OO];
    float wi[2][DD];
#pragma unroll
    for (int d = 0; d < DD; ++d) {
        wi[0][d] = Wi2h[j0 * DD + d];
        wi[1][d] = Wi2h[(j0 + 1) * DD + d];
    }
    float wo[2][OO];
#pragma unroll
    for (int o = 0; o < OO; ++o) {
        wo[0][o] = Wh2o[o * HH + j0];
        wo[1][o] = Wh2o[o * HH + j0 + 1];
    }
    float h[2] = { h0[b * HH + j0], h0[b * HH + j0 + 1] };
    th[j0] = tanhf(h[0]); th[j0 + 1] = tanhf(h[1]);
    if (t0 < DD) xs[t0] = x[(size_t)(b * TT) * DD + t0];
    __syncthreads();
    for (int t = 0; t < TT; ++t) {
        float a0 = 0.f, a1 = 0.f;
        const float* r0 = W + (size_t)j0 * HH;
        const float* r1 = W + (size_t)(j0 + 1) * HH;
#pragma unroll 4
        for (int k = 0; k < HH; k += 4) {
            float4 t4 = *(const float4*)&th[k];
            float4 wA = *(const float4*)(r0 + k);
            float4 wB = *(const float4*)(r1 + k);
            a0 += t4.x * wA.x + t4.y * wA.y + t4.z * wA.z + t4.w * wA.w;
            a1 += t4.x * wB.x + t4.y * wB.y + t4.z * wB.z + t4.w * wB.w;
        }
        float xp0 = 0.f, xp1 = 0.f;
#pragma unroll
        for (int d = 0; d < DD; ++d) { xp0 += xs[d] * wi[0][d]; xp1 += xs[d] * wi[1][d]; }
        h[0] = 0.9f * h[0] + 0.1f * (a0 + xp0);
        h[1] = 0.9f * h[1] + 0.1f * (a1 + xp1);
        float th0 = tanhf(h[0]), th1 = tanhf(h[1]);
        *(float2*)&out_h[((size_t)b * TT + t) * HH + j0] = make_float2(h[0], h[1]);
        float po[OO];
#pragma unroll
        for (int o = 0; o < OO; ++o) po[o] = th0 * wo[0][o] + th1 * wo[1][o];
#pragma unroll
        for (int s = 32; s; s >>= 1)
#pragma unroll
            for (int o = 0; o < OO; ++o) po[o] += __shfl_down(po[o], s, 64);
        __syncthreads();
        if (lane == 0)
#pragma unroll
            for (int o = 0; o < OO; ++o) ored[wave][o] = po[o];
        th[j0] = th0; th[j0 + 1] = th1;
        if (t0 < DD && t + 1 < TT) xs[t0] = x[(size_t)(b * TT + t + 1) * DD + t0];
        __syncthreads();
        if (t0 < OO) {
            float s = 0.f;
#pragma unroll
            for (int ww = 0; ww < 8; ++ww) s += ored[ww][t0];
            out_o[((size_t)b * TT + t) * OO + t0] = s;
        }
    }
}

extern "C" void kernel_launch(void* const* d_in, const int* in_sizes, int n_in,
                              void* d_out, int out_size, void* d_ws, size_t ws_size,
                              hipStream_t stream) {
    const float* x    = (const float*)d_in[0];
    const float* h0   = (const float*)d_in[1];
    const float* Wi2h = (const float*)d_in[2];
    const float* Wh2h = (const float*)d_in[3];
    const float* Wh2o = (const float*)d_in[4];

    float* out_o = (float*)d_out;                    // [64][1000][8]
    float* out_h = out_o + (size_t)BB * TT * OO;     // [64][1000][1024]

    const size_t th_bytes = (size_t)2 * NGRP * HH * GB * sizeof(float);  // 512 KB
    const size_t need     = th_bytes + NGRP * sizeof(unsigned);

    if (ws_size >= need) {
        float*    TH  = (float*)d_ws;
        unsigned* cnt = (unsigned*)((char*)d_ws + th_bytes);
        hipMemsetAsync(cnt, 0, NGRP * sizeof(unsigned), stream);
        rnn_coop<<<NBLK, NTH, 0, stream>>>(x, h0, Wi2h, Wh2h, out_h, TH, cnt);
        h2o_kernel<<<2048, 256, 0, stream>>>(out_h, Wh2o, out_o);
    } else {
        rnn_fallback<<<BB, 512, 0, stream>>>(x, h0, Wi2h, Wh2h, Wh2o, out_o, out_h);
    }
}

// Round 3
// 20071.965 us; speedup vs baseline: 3.7902x; 1.3085x over previous
//
#include <hip/hip_runtime.h>
#include <hip/hip_bf16.h>

#define BB 64
#define TT 1000
#define DD 16
#define HH 1024
#define OO 8

#define NGRP 4          // batch groups (16 batches each)
#define GB   16         // batches per group
#define NBLK 256        // NGRP * (HH/16)
#define NTH  512

// ---------------------------------------------------------------------------
// Persistent cooperative RNN kernel, W_h2h in registers.
// Block (bg, js): batches [bg*16,+16), units [js*16,+16).
// Lane tile: J=4 (j4), B=4 (b4), K=32 (k4 splits wave's 128-k stripe).
//   lane = j4 | b4<<2 | k4<<4  (k4 in bits 4-5 -> xor16/xor32 reduce)
// th exchanged via TH[2][NGRP][GB][HH] (b-major) with device-scope (sc1)
// scalar stores; per-(block,finalize-wave) flags; relaxed polls + one
// acquire fence. Safety of the 2-deep TH ring: a block's finalize(t) writes
// buffer p^1 only after its step-t barrier, which requires all its waves'
// polls (covering ALL 64 producer blocks) at level t -> every block has
// finished reading buffer p^1 (their step t-1 reads) before any overwrite.
// ---------------------------------------------------------------------------
__global__ __launch_bounds__(NTH, 2) void rnn_coop(
    const float* __restrict__ x,     // [64][1000][16]
    const float* __restrict__ h0,    // [64][1024]
    const float* __restrict__ Wi2h,  // [1024][16]
    const float* __restrict__ Wh2h,  // [1024][1024]
    float* __restrict__ out_h,       // [64][1000][1024]
    float* TH,                       // [2][NGRP][GB][HH]
    unsigned* flags)                 // [2][NGRP][64][4]
{
    // THl[w][k4][b][36]: wave-private th stripes. Row stride 36 floats
    // (144B, 16B-aligned); quad swizzle kk' = kq ^ k4 spreads the k4-groups
    // across bank-groups -> conflict-free b128 reads/writes.
    __shared__ __align__(16) float THl[8][4][16][36];   // 73.7 KB
    __shared__ float SC[2][16][16][9];                  // 18.4 KB [p][b][j][w]
    __shared__ float XS[2][16][20];                     // 2.6 KB  [p][b][d]

    const int tid = threadIdx.x;
    const int w   = tid >> 6;
    const int l   = tid & 63;
    const int bid = blockIdx.x;
    const int bg  = bid & (NGRP - 1);
    const int js  = bid >> 2;

    const int j4 = l & 3;
    const int b4 = (l >> 2) & 3;
    const int k4 = l >> 4;
    const int jbase = js * 16 + j4 * 4;
    const int kbase = w * 128 + k4 * 32;

    // ---- W slice -> registers (128 VGPR). Static indexing only. ----
    float4 w4[4][8];
#pragma unroll
    for (int jj = 0; jj < 4; ++jj)
#pragma unroll
        for (int kq = 0; kq < 8; ++kq)
            w4[jj][kq] = *(const float4*)&Wh2h[(size_t)(jbase + jj) * HH + kbase + kq * 4];

    // ---- finalize-thread state: tid<256 owns (fj = tid&15, fb = tid>>4) ----
    const int fj = tid & 15, fb = tid >> 4;
    float h = 0.f;
    float wi[DD];
    if (tid < 256) {
        h = h0[(size_t)(bg * GB + fb) * HH + js * 16 + fj];
#pragma unroll
        for (int d = 0; d < DD; ++d) wi[d] = Wi2h[(js * 16 + fj) * DD + d];
        float th0 = tanhf(h);
        __hip_atomic_store(&TH[((size_t)(0 * NGRP + bg) * GB + fb) * HH + js * 16 + fj],
                           th0, __ATOMIC_RELAXED, __HIP_MEMORY_SCOPE_AGENT);
    }
    if (w < 4) {
        asm volatile("s_waitcnt vmcnt(0)" ::: "memory");   // th stores at LLC
        if (l == 0)
            __hip_atomic_store(&flags[((size_t)(0 * NGRP + bg) * 64 + js) * 4 + w],
                               1u, __ATOMIC_RELAXED, __HIP_MEMORY_SCOPE_AGENT);
    }

    for (int t = 0; t < TT; ++t) {
        const int p = t & 1;

        // ---- dataflow poll: wave w needs producers js' in [8w, 8w+8) ----
        {
            const unsigned target = (unsigned)(t + 1);
            const unsigned* fa = flags +
                ((size_t)(p * NGRP + bg) * 64 + (8 * w + (l >> 2))) * 4 + (l & 3);
            for (;;) {
                unsigned v = target;
                if (l < 32)
                    v = __hip_atomic_load(fa, __ATOMIC_RELAXED, __HIP_MEMORY_SCOPE_AGENT);
                if (__all((int)(v >= target))) break;
                __builtin_amdgcn_s_sleep(1);
            }
        }
        __builtin_amdgcn_fence(__ATOMIC_ACQUIRE, "agent");  // inv stale lines

        // ---- stage wave's 128-k stripe of th: global [b][k] -> THl[w] ----
        {
            const float* THr = TH + (size_t)(p * NGRP + bg) * GB * HH;
            const int sb = l & 15, sq = l >> 4;
#pragma unroll
            for (int i = 0; i < 8; ++i) {
                int Q = sq + 4 * i;                       // quad 0..31 in stripe
                float4 v = *(const float4*)&THr[(size_t)sb * HH + w * 128 + Q * 4];
                int k4s = Q >> 3, kks = (Q & 7) ^ k4s;    // swizzled quad
                *(float4*)&THl[w][k4s][sb][kks * 4] = v;
            }
        }
        if (w == 0) {   // stage x tile for this step
            int sb = l >> 2, dq = (l & 3) * 4;
            float4 v = *(const float4*)&x[((size_t)(bg * GB + sb) * TT + t) * DD + dq];
            *(float4*)&XS[p][sb][dq] = v;
        }
        asm volatile("s_waitcnt vmcnt(0) lgkmcnt(0)" ::: "memory");

        // ---- compute: acc[jj][m] over lane's 32-k slice (512 FMA) ----
        float acc[4][4];
#pragma unroll
        for (int jj = 0; jj < 4; ++jj)
#pragma unroll
            for (int m = 0; m < 4; ++m) acc[jj][m] = 0.f;
#pragma unroll
        for (int kq = 0; kq < 8; ++kq) {
            const int kks = ((kq ^ k4) * 4);
#pragma unroll
            for (int m = 0; m < 4; ++m) {
                float4 tv = *(const float4*)&THl[w][k4][b4 * 4 + m][kks];
#pragma unroll
                for (int jj = 0; jj < 4; ++jj) {
                    acc[jj][m] += w4[jj][kq].x * tv.x;
                    acc[jj][m] += w4[jj][kq].y * tv.y;
                    acc[jj][m] += w4[jj][kq].z * tv.z;
                    acc[jj][m] += w4[jj][kq].w * tv.w;
                }
            }
        }

        // ---- reduce over k4 (lanes ^16 via swizzle, ^32 via permlane) ----
#pragma unroll
        for (int jj = 0; jj < 4; ++jj)
#pragma unroll
            for (int m = 0; m < 4; ++m) {
                float a = acc[jj][m];
                a += __shfl_xor(a, 16, 64);
                a += __shfl_xor(a, 32, 64);
                acc[jj][m] = a;
            }
        if (k4 == 0) {
#pragma unroll
            for (int m = 0; m < 4; ++m)
#pragma unroll
                for (int jj = 0; jj < 4; ++jj)
                    SC[p][b4 * 4 + m][j4 * 4 + jj][w] = acc[jj][m];
        }

        __syncthreads();   // the ONE per-step block barrier (SC + XS publish)

        // ---- finalize: h update, out_h, th for next step ----
        if (tid < 256) {
            float z = 0.f;
#pragma unroll
            for (int ww = 0; ww < 8; ++ww) z += SC[p][fb][fj][ww];
            float xp = 0.f;
#pragma unroll
            for (int d = 0; d < DD; ++d) xp += wi[d] * XS[p][fb][d];
            h = 0.9f * h + 0.1f * (z + xp);
            float th = tanhf(h);
            out_h[((size_t)(bg * GB + fb) * TT + t) * HH + js * 16 + fj] = h;
            __hip_atomic_store(
                &TH[((size_t)((p ^ 1) * NGRP + bg) * GB + fb) * HH + js * 16 + fj],
                th, __ATOMIC_RELAXED, __HIP_MEMORY_SCOPE_AGENT);
        }
        if (w < 4 && t + 1 < TT) {
            asm volatile("s_waitcnt vmcnt(0)" ::: "memory");  // th at LLC
            if (l == 0)
                __hip_atomic_store(
                    &flags[((size_t)((p ^ 1) * NGRP + bg) * 64 + js) * 4 + w],
                    (unsigned)(t + 2), __ATOMIC_RELAXED, __HIP_MEMORY_SCOPE_AGENT);
        }
    }
}

// ---------------------------------------------------------------------------
// h2o output kernel: out[b][t][o] = sum_j tanh(h[b][t][j]) * Wh2o[o][j]
// ---------------------------------------------------------------------------
__global__ __launch_bounds__(256) void h2o_kernel(
    const float* __restrict__ hs,    // [64][1000][1024]
    const float* __restrict__ Wh2o,  // [8][1024]
    float* __restrict__ out_o)       // [64][1000][8]
{
    __shared__ float Wl[OO * HH];
    for (int i = threadIdx.x; i < OO * HH; i += 256) Wl[i] = Wh2o[i];
    __syncthreads();

    const int w = threadIdx.x >> 6, l = threadIdx.x & 63;
    const size_t nrows = (size_t)BB * TT;
    for (size_t row = (size_t)blockIdx.x * 4 + w; row < nrows; row += (size_t)gridDim.x * 4) {
        const float* hr = hs + row * HH;
        float po[OO] = {0.f};
#pragma unroll
        for (int i = 0; i < 16; ++i) {
            int j = l + 64 * i;
            float th = tanhf(hr[j]);
#pragma unroll
            for (int o = 0; o < OO; ++o) po[o] += th * Wl[o * HH + j];
        }
#pragma unroll
        for (int s = 32; s; s >>= 1)
#pragma unroll
            for (int o = 0; o < OO; ++o) po[o] += __shfl_down(po[o], s, 64);
        if (l == 0) {
#pragma unroll
            for (int o = 0; o < OO; ++o) out_o[row * OO + o] = po[o];
        }
    }
}

// ---------------------------------------------------------------------------
// Fallback (round-1 style) if ws is too small.
// ---------------------------------------------------------------------------
__global__ __launch_bounds__(512) void rnn_fallback(
    const float* __restrict__ x, const float* __restrict__ h0,
    const float* __restrict__ Wi2h, const float* __restrict__ W,
    const float* __restrict__ Wh2o, float* __restrict__ out_o,
    float* __restrict__ out_h)
{
    const int b = blockIdx.x, t0 = threadIdx.x, j0 = 2 * t0;
    const int wave = t0 >> 6, lane = t0 & 63;
    __shared__ float th[HH];
    __shared__ float xs[DD];
    __shared__ float ored[8][OO];
    float wi[2][DD];
#pragma unroll
    for (int d = 0; d < DD; ++d) {
        wi[0][d] = Wi2h[j0 * DD + d];
        wi[1][d] = Wi2h[(j0 + 1) * DD + d];
    }
    float wo[2][OO];
#pragma unroll
    for (int o = 0; o < OO; ++o) {
        wo[0][o] = Wh2o[o * HH + j0];
        wo[1][o] = Wh2o[o * HH + j0 + 1];
    }
    float h[2] = { h0[b * HH + j0], h0[b * HH + j0 + 1] };
    th[j0] = tanhf(h[0]); th[j0 + 1] = tanhf(h[1]);
    if (t0 < DD) xs[t0] = x[(size_t)(b * TT) * DD + t0];
    __syncthreads();
    for (int t = 0; t < TT; ++t) {
        float a0 = 0.f, a1 = 0.f;
        const float* r0 = W + (size_t)j0 * HH;
        const float* r1 = W + (size_t)(j0 + 1) * HH;
#pragma unroll 4
        for (int k = 0; k < HH; k += 4) {
            float4 t4 = *(const float4*)&th[k];
            float4 wA = *(const float4*)(r0 + k);
            float4 wB = *(const float4*)(r1 + k);
            a0 += t4.x * wA.x + t4.y * wA.y + t4.z * wA.z + t4.w * wA.w;
            a1 += t4.x * wB.x + t4.y * wB.y + t4.z * wB.z + t4.w * wB.w;
        }
        float xp0 = 0.f, xp1 = 0.f;
#pragma unroll
        for (int d = 0; d < DD; ++d) { xp0 += xs[d] * wi[0][d]; xp1 += xs[d] * wi[1][d]; }
        h[0] = 0.9f * h[0] + 0.1f * (a0 + xp0);
        h[1] = 0.9f * h[1] + 0.1f * (a1 + xp1);
        float th0 = tanhf(h[0]), th1 = tanhf(h[1]);
        *(float2*)&out_h[((size_t)b * TT + t) * HH + j0] = make_float2(h[0], h[1]);
        float po[OO];
#pragma unroll
        for (int o = 0; o < OO; ++o) po[o] = th0 * wo[0][o] + th1 * wo[1][o];
#pragma unroll
        for (int s = 32; s; s >>= 1)
#pragma unroll
            for (int o = 0; o < OO; ++o) po[o] += __shfl_down(po[o], s, 64);
        __syncthreads();
        if (lane == 0)
#pragma unroll
            for (int o = 0; o < OO; ++o) ored[wave][o] = po[o];
        th[j0] = th0; th[j0 + 1] = th1;
        if (t0 < DD && t + 1 < TT) xs[t0] = x[(size_t)(b * TT + t + 1) * DD + t0];
        __syncthreads();
        if (t0 < OO) {
            float s = 0.f;
#pragma unroll
            for (int ww = 0; ww < 8; ++ww) s += ored[ww][t0];
            out_o[((size_t)b * TT + t) * OO + t0] = s;
        }
    }
}

extern "C" void kernel_launch(void* const* d_in, const int* in_sizes, int n_in,
                              void* d_out, int out_size, void* d_ws, size_t ws_size,
                              hipStream_t stream) {
    const float* x    = (const float*)d_in[0];
    const float* h0   = (const float*)d_in[1];
    const float* Wi2h = (const float*)d_in[2];
    const float* Wh2h = (const float*)d_in[3];
    const float* Wh2o = (const float*)d_in[4];

    float* out_o = (float*)d_out;                    // [64][1000][8]
    float* out_h = out_o + (size_t)BB * TT * OO;     // [64][1000][1024]

    const size_t th_bytes   = (size_t)2 * NGRP * GB * HH * sizeof(float);  // 512 KB
    const size_t flag_bytes = (size_t)2 * NGRP * 64 * 4 * sizeof(unsigned); // 8 KB
    const size_t need       = th_bytes + flag_bytes;

    if (ws_size >= need) {
        float*    TH  = (float*)d_ws;
        unsigned* flg = (unsigned*)((char*)d_ws + th_bytes);
        hipMemsetAsync(flg, 0, flag_bytes, stream);
        rnn_coop<<<NBLK, NTH, 0, stream>>>(x, h0, Wi2h, Wh2h, out_h, TH, flg);
        h2o_kernel<<<2048, 256, 0, stream>>>(out_h, Wh2o, out_o);
    } else {
        rnn_fallback<<<BB, 512, 0, stream>>>(x, h0, Wi2h, Wh2h, Wh2o, out_o, out_h);
    }
}

// Round 5
// 5409.012 us; speedup vs baseline: 14.0649x; 3.7108x over previous
//
#include <hip/hip_runtime.h>
#include <hip/hip_bf16.h>

#define BB 64
#define TT 1000
#define DD 16
#define HH 1024
#define OO 8

#define NGRP 16         // batch groups
#define GB   4          // batches per group
#define SJ   64         // j-units per block
#define NJS  16         // blocks per group = HH/SJ
#define NBLK 256        // NGRP * NJS
#define NTH  512

// ---------------------------------------------------------------------------
// Persistent cooperative RNN. Block (bg, js): batches [bg*4,+4), units
// [js*64,+64). W slice (64x1024) lives in VGPRs (128 floats/lane).
// Wave w owns k-stripe [w*128,+128); lane = j16 (l&15) x k4 (l>>4):
// per lane 4j x 4b x 32k = 512 FMA/step.
// th exchange: TH[2][NGRP][GB][HH] via relaxed-agent scalar stores (sc1,
// write-through LLC) + per-(js,wave) flags (64B-padded lines); consumers
// read TH with inline-asm sc0 sc1 dwordx4 loads (LLC-direct, no fence, no
// L2 invalidate). Ring safety: block X's flag at level t transitively
// certifies X finished all its step t-1 stage reads (they precede X's
// barrier(t-1) which precedes X's finalize flag) -> no WAR on the 2-deep
// ring. One __syncthreads per step (SC/XS publish).
// ---------------------------------------------------------------------------
__global__ __launch_bounds__(NTH, 2) void rnn_coop(
    const float* __restrict__ x,     // [64][1000][16]
    const float* __restrict__ h0,    // [64][1024]
    const float* __restrict__ Wi2h,  // [1024][16]
    const float* Wh2h,               // [1024][1024]  (no restrict: pins W regs)
    float* __restrict__ out_h,       // [64][1000][1024]
    float* TH,                       // [2][NGRP][GB][HH]
    unsigned* flags)                 // [2][NGRP][NJS][16]  (64B per js)
{
    __shared__ __align__(16) float THl[8][4][GB][36];   // 18.4 KB wave-private
    __shared__ float SC[2][GB][SJ][9];                  // 18.4 KB [p][b][j][w]
    __shared__ float XS[2][GB][20];                     // [p][b][d]

    const int tid = threadIdx.x;
    const int w   = tid >> 6;
    const int l   = tid & 63;
    const int bid = blockIdx.x;
    const int bg  = bid & (NGRP - 1);
    const int js  = bid >> 4;         // 0..15

    const int j16 = l & 15;
    const int k4  = l >> 4;           // 0..3 (bits 4-5 -> xor16/xor32 reduce)
    const int jbase = js * SJ + j16 * 4;
    const int kbase = w * 128 + k4 * 32;

    // ---- W slice -> registers (32 float4 = 128 VGPR) ----
    float4 w4[4][8];
#pragma unroll
    for (int jj = 0; jj < 4; ++jj)
#pragma unroll
        for (int kq = 0; kq < 8; ++kq)
            w4[jj][kq] = *(const float4*)&Wh2h[(size_t)(jbase + jj) * HH + kbase + kq * 4];
    // keep-alive: scalar tied operands only (vector "+v" is unsupported)
#pragma unroll
    for (int jj = 0; jj < 4; ++jj)
#pragma unroll
        for (int kq = 0; kq < 8; ++kq)
            asm volatile("" : "+v"(w4[jj][kq].x), "+v"(w4[jj][kq].y),
                             "+v"(w4[jj][kq].z), "+v"(w4[jj][kq].w));

    // ---- finalize role: tid<256 owns (fb = wave = tid>>6, fj = tid&63) ----
    const int fb = tid >> 6, fj = tid & 63;
    float h = 0.f;
    float wi[DD];
    if (tid < 256) {
        h = h0[(size_t)(bg * GB + fb) * HH + js * SJ + fj];
#pragma unroll
        for (int d = 0; d < DD; ++d) wi[d] = Wi2h[(js * SJ + fj) * DD + d];
        float th0 = tanhf(h);
        __hip_atomic_store(&TH[((size_t)(0 * NGRP + bg) * GB + fb) * HH + js * SJ + fj],
                           th0, __ATOMIC_RELAXED, __HIP_MEMORY_SCOPE_AGENT);
        asm volatile("s_waitcnt vmcnt(0)" ::: "memory");
        if (l == 0)
            __hip_atomic_store(&flags[((size_t)(0 * NGRP + bg) * NJS + js) * 16 + fb],
                               1u, __ATOMIC_RELAXED, __HIP_MEMORY_SCOPE_AGENT);
    }

    for (int t = 0; t < TT; ++t) {
        const int p = t & 1;

        // ---- poll: wave w needs producers js' in {2w, 2w+1} (8 lanes) ----
        {
            const unsigned target = (unsigned)(t + 1);
            const unsigned* fa = flags +
                ((size_t)(p * NGRP + bg) * NJS + (2 * w + (l >> 2))) * 16 + (l & 3);
            for (;;) {
                unsigned v = target;
                if (l < 8)
                    v = __hip_atomic_load(fa, __ATOMIC_RELAXED, __HIP_MEMORY_SCOPE_AGENT);
                if (__all((int)(v >= target))) break;
                __builtin_amdgcn_s_sleep(1);
            }
        }

        // ---- stage wave's 128-k stripe: LLC-direct sc1 loads, no fence ----
        {
            const int sb = l >> 4, sq = l & 15;
            const float* base = TH + ((size_t)(p * NGRP + bg) * GB + sb) * HH + w * 128;
            const float* a0 = base + sq * 4;          // quad Q = sq
            const float* a1 = base + (sq + 16) * 4;   // quad Q = sq+16
            float4 v0, v1;
            asm volatile("global_load_dwordx4 %0, %2, off sc0 sc1\n\t"
                         "global_load_dwordx4 %1, %3, off sc0 sc1\n\t"
                         "s_waitcnt vmcnt(0)"
                         : "=&v"(v0), "=&v"(v1)
                         : "v"(a0), "v"(a1)
                         : "memory");
            int k40 = sq >> 3,        kk0 = (sq & 7) ^ k40;
            int k41 = (sq + 16) >> 3, kk1 = (sq & 7) ^ k41;   // (Q1&7)==sq&7
            *(float4*)&THl[w][k40][sb][kk0 * 4] = v0;
            *(float4*)&THl[w][k41][sb][kk1 * 4] = v1;
        }
        if (w == 0) {   // stage x tile (plain loads; x stays L2-warm)
            int sb = l >> 2, dq = (l & 3) * 4;
            if (l < 16) {
                float4 v = *(const float4*)&x[((size_t)(bg * GB + sb) * TT + t) * DD + dq];
                *(float4*)&XS[p][sb][dq] = v;
            }
        }
        asm volatile("s_waitcnt lgkmcnt(0)" ::: "memory");
        __builtin_amdgcn_sched_barrier(0);

        // ---- compute: acc[jj][m] over lane's 32-k slice (512 FMA) ----
        float acc[4][4];
#pragma unroll
        for (int jj = 0; jj < 4; ++jj)
#pragma unroll
            for (int m = 0; m < 4; ++m) acc[jj][m] = 0.f;
#pragma unroll
        for (int kq = 0; kq < 8; ++kq) {
            const int kks = (kq ^ k4) * 4;
#pragma unroll
            for (int m = 0; m < 4; ++m) {
                float4 tv = *(const float4*)&THl[w][k4][m][kks];
#pragma unroll
                for (int jj = 0; jj < 4; ++jj) {
                    acc[jj][m] += w4[jj][kq].x * tv.x;
                    acc[jj][m] += w4[jj][kq].y * tv.y;
                    acc[jj][m] += w4[jj][kq].z * tv.z;
                    acc[jj][m] += w4[jj][kq].w * tv.w;
                }
            }
        }

        // ---- reduce over k4 (xor16, xor32) and publish per-wave sums ----
#pragma unroll
        for (int jj = 0; jj < 4; ++jj)
#pragma unroll
            for (int m = 0; m < 4; ++m) {
                float a = acc[jj][m];
                a += __shfl_xor(a, 16, 64);
                a += __shfl_xor(a, 32, 64);
                acc[jj][m] = a;
            }
        if (k4 == 0) {
#pragma unroll
            for (int m = 0; m < 4; ++m)
#pragma unroll
                for (int jj = 0; jj < 4; ++jj)
                    SC[p][m][j16 * 4 + jj][w] = acc[jj][m];
        }

        __syncthreads();   // the ONE per-step block barrier

        // ---- finalize (waves 0-3): h update, TH+flag, then out_h ----
        if (tid < 256) {
            float z = 0.f;
#pragma unroll
            for (int ww = 0; ww < 8; ++ww) z += SC[p][fb][fj][ww];
            float xp = 0.f;
#pragma unroll
            for (int d = 0; d < DD; ++d) xp += wi[d] * XS[p][fb][d];
            h = 0.9f * h + 0.1f * (z + xp);
            float th = tanhf(h);
            __hip_atomic_store(
                &TH[((size_t)((p ^ 1) * NGRP + bg) * GB + fb) * HH + js * SJ + fj],
                th, __ATOMIC_RELAXED, __HIP_MEMORY_SCOPE_AGENT);
            asm volatile("s_waitcnt vmcnt(0)" ::: "memory");
            if (l == 0 && t + 1 < TT)
                __hip_atomic_store(
                    &flags[((size_t)((p ^ 1) * NGRP + bg) * NJS + js) * 16 + fb],
                    (unsigned)(t + 2), __ATOMIC_RELAXED, __HIP_MEMORY_SCOPE_AGENT);
            out_h[((size_t)(bg * GB + fb) * TT + t) * HH + js * SJ + fj] = h;
        }
    }
}

// ---------------------------------------------------------------------------
// h2o output kernel: out[b][t][o] = sum_j tanh(h[b][t][j]) * Wh2o[o][j]
// ---------------------------------------------------------------------------
__global__ __launch_bounds__(256) void h2o_kernel(
    const float* __restrict__ hs,    // [64][1000][1024]
    const float* __restrict__ Wh2o,  // [8][1024]
    float* __restrict__ out_o)       // [64][1000][8]
{
    __shared__ float Wl[OO * HH];
    for (int i = threadIdx.x; i < OO * HH; i += 256) Wl[i] = Wh2o[i];
    __syncthreads();

    const int w = threadIdx.x >> 6, l = threadIdx.x & 63;
    const size_t nrows = (size_t)BB * TT;
    for (size_t row = (size_t)blockIdx.x * 4 + w; row < nrows; row += (size_t)gridDim.x * 4) {
        const float* hr = hs + row * HH;
        float po[OO] = {0.f};
#pragma unroll
        for (int i = 0; i < 16; ++i) {
            int j = l + 64 * i;
            float th = tanhf(hr[j]);
#pragma unroll
            for (int o = 0; o < OO; ++o) po[o] += th * Wl[o * HH + j];
        }
#pragma unroll
        for (int s = 32; s; s >>= 1)
#pragma unroll
            for (int o = 0; o < OO; ++o) po[o] += __shfl_down(po[o], s, 64);
        if (l == 0) {
#pragma unroll
            for (int o = 0; o < OO; ++o) out_o[row * OO + o] = po[o];
        }
    }
}

// ---------------------------------------------------------------------------
// Fallback (round-1 style) if ws is too small.
// ---------------------------------------------------------------------------
__global__ __launch_bounds__(512) void rnn_fallback(
    const float* __restrict__ x, const float* __restrict__ h0,
    const float* __restrict__ Wi2h, const float* __restrict__ W,
    const float* __restrict__ Wh2o, float* __restrict__ out_o,
    float* __restrict__ out_h)
{
    const int b = blockIdx.x, t0 = threadIdx.x, j0 = 2 * t0;
    const int wave = t0 >> 6, lane = t0 & 63;
    __shared__ float th[HH];
    __shared__ float xs[DD];
    __shared__ float ored[8][OO];
    float wi[2][DD];
#pragma unroll
    for (int d = 0; d < DD; ++d) {
        wi[0][d] = Wi2h[j0 * DD + d];
        wi[1][d] = Wi2h[(j0 + 1) * DD + d];
    }
    float wo[2][OO];
#pragma unroll
    for (int o = 0; o < OO; ++o) {
        wo[0][o] = Wh2o[o * HH + j0];
        wo[1][o] = Wh2o[o * HH + j0 + 1];
    }
    float h[2] = { h0[b * HH + j0], h0[b * HH + j0 + 1] };
    th[j0] = tanhf(h[0]); th[j0 + 1] = tanhf(h[1]);
    if (t0 < DD) xs[t0] = x[(size_t)(b * TT) * DD + t0];
    __syncthreads();
    for (int t = 0; t < TT; ++t) {
        float a0 = 0.f, a1 = 0.f;
        const float* r0 = W + (size_t)j0 * HH;
        const float* r1 = W + (size_t)(j0 + 1) * HH;
#pragma unroll 4
        for (int k = 0; k < HH; k += 4) {
            float4 t4 = *(const float4*)&th[k];
            float4 wA = *(const float4*)(r0 + k);
            float4 wB = *(const float4*)(r1 + k);
            a0 += t4.x * wA.x + t4.y * wA.y + t4.z * wA.z + t4.w * wA.w;
            a1 += t4.x * wB.x + t4.y * wB.y + t4.z * wB.z + t4.w * wB.w;
        }
        float xp0 = 0.f, xp1 = 0.f;
#pragma unroll
        for (int d = 0; d < DD; ++d) { xp0 += xs[d] * wi[0][d]; xp1 += xs[d] * wi[1][d]; }
        h[0] = 0.9f * h[0] + 0.1f * (a0 + xp0);
        h[1] = 0.9f * h[1] + 0.1f * (a1 + xp1);
        float th0 = tanhf(h[0]), th1 = tanhf(h[1]);
        *(float2*)&out_h[((size_t)b * TT + t) * HH + j0] = make_float2(h[0], h[1]);
        float po[OO];
#pragma unroll
        for (int o = 0; o < OO; ++o) po[o] = th0 * wo[0][o] + th1 * wo[1][o];
#pragma unroll
        for (int s = 32; s; s >>= 1)
#pragma unroll
            for (int o = 0; o < OO; ++o) po[o] += __shfl_down(po[o], s, 64);
        __syncthreads();
        if (lane == 0)
#pragma unroll
            for (int o = 0; o < OO; ++o) ored[wave][o] = po[o];
        th[j0] = th0; th[j0 + 1] = th1;
        if (t0 < DD && t + 1 < TT) xs[t0] = x[(size_t)(b * TT + t + 1) * DD + t0];
        __syncthreads();
        if (t0 < OO) {
            float s = 0.f;
#pragma unroll
            for (int ww = 0; ww < 8; ++ww) s += ored[ww][t0];
            out_o[((size_t)b * TT + t) * OO + t0] = s;
        }
    }
}

extern "C" void kernel_launch(void* const* d_in, const int* in_sizes, int n_in,
                              void* d_out, int out_size, void* d_ws, size_t ws_size,
                              hipStream_t stream) {
    const float* x    = (const float*)d_in[0];
    const float* h0   = (const float*)d_in[1];
    const float* Wi2h = (const float*)d_in[2];
    const float* Wh2h = (const float*)d_in[3];
    const float* Wh2o = (const float*)d_in[4];

    float* out_o = (float*)d_out;                    // [64][1000][8]
    float* out_h = out_o + (size_t)BB * TT * OO;     // [64][1000][1024]

    const size_t th_bytes   = (size_t)2 * NGRP * GB * HH * sizeof(float);      // 512 KB
    const size_t flag_bytes = (size_t)2 * NGRP * NJS * 16 * sizeof(unsigned);  // 32 KB
    const size_t need       = th_bytes + flag_bytes;

    if (ws_size >= need) {
        float*    TH  = (float*)d_ws;
        unsigned* flg = (unsigned*)((char*)d_ws + th_bytes);
        hipMemsetAsync(flg, 0, flag_bytes, stream);
        rnn_coop<<<NBLK, NTH, 0, stream>>>(x, h0, Wi2h, Wh2h, out_h, TH, flg);
        h2o_kernel<<<2048, 256, 0, stream>>>(out_h, Wh2o, out_o);
    } else {
        rnn_fallback<<<BB, 512, 0, stream>>>(x, h0, Wi2h, Wh2h, Wh2o, out_o, out_h);
    }
}